// Round 11
// baseline (1010.277 us; speedup 1.0000x reference)
//
#include <hip/hip_runtime.h>
#include <math.h>

#define CC 20
#define BB 256
#define HH 10
#define SS 64
#define AA 16
#define HD 128
#define RH 64
#define CBR (CC*BB)      // 5120 rows
#define NSNN 15
#define RT 2             // rows per block, one wave-pair per row

// Dynamic-LDS layout, per row (floats):
#define ROW_F     1504
#define OFF_STATE 0      // 64
#define OFF_SAE   64     // 256
#define OFF_MASK  320    // 128 (as unsigned)
#define OFF_MEM2  448    // 128
#define OFF_MU    576    // 128
#define OFF_X     704    // 80
#define OFF_H     784    // 64
#define OFF_H2A   848    // 10*64
#define OFF_R     1488   // 16

__device__ __forceinline__ float* rowbase(int r) {
    extern __shared__ float smem[];
    return smem + r * ROW_F;
}

// Replicate npy_logaddexpf(u, 0.f): float32 chain, expf/log1pf at
// correctly-rounded level via f64 internals. (Verified bit-exact rounds 4-10.)
__device__ __forceinline__ float softplus_np(float u) {
    if (u > 0.0f) {
        float ef = (float)exp((double)(-u));
        float l1 = (float)log1p((double)ef);
        return __fadd_rn(u, l1);
    } else if (u < 0.0f) {
        float ef = (float)exp((double)u);
        return (float)log1p((double)ef);
    } else {
        return 0.69314718055994530942f;
    }
}

// ---- Phase functions. __noinline__ is the regalloc firewall: rounds 5/7
// showed the compiler software-pipelines across fused phases and explodes
// to ~200 VGPR; opaque calls cap the kernel at max(per-phase) ~= 40-50.
// All arithmetic chains are verbatim from the bit-exact round-10 kernel.

__device__ __attribute__((noinline)) void phase_encode(
    int j, int r, int cb, int h,
    const float* __restrict__ Wse, const float* __restrict__ bse,
    const float* __restrict__ Wae, const float* __restrict__ bae,
    const float* __restrict__ actions)
{
    float* R = rowbase(r);
    float* s_state = R + OFF_STATE;
    float* s_sae   = R + OFF_SAE;
    float* s_x     = R + OFF_X;

    // se = relu(state @ Wse + bse): sequential-k single chain
    float acc = 0.0f;
    for (int i = 0; i < SS; i++)
        acc = fmaf(s_state[i], Wse[i*HD + j], acc);
    float se = fmaxf(__fadd_rn(acc, bse[j]), 0.0f);

    // ae = relu(act @ Wae + bae)
    const float* act = actions + ((size_t)cb*HH + h)*AA;
    acc = 0.0f;
    for (int i = 0; i < AA; i++)
        acc = fmaf(act[i], Wae[i*HD + j], acc);
    float ae = fmaxf(__fadd_rn(acc, bae[j]), 0.0f);

    s_sae[j]      = se;
    s_sae[HD + j] = ae;
    if (j < AA) s_x[SS + j] = act[j];   // action part of reward input, step h
}

__device__ __attribute__((noinline)) void phase_curmask(
    int j, int r, const float* __restrict__ W1, const float* __restrict__ b1)
{
    float* R = rowbase(r);
    float* s_sae = R + OFF_SAE;
    unsigned* s_mask = (unsigned*)(R + OFF_MASK);

    // cur = concat(se, ae) @ W1 + b1 (constant across SNN steps)
    float acc = 0.0f;
    for (int i = 0; i < 2*HD; i++)
        acc = fmaf(s_sae[i], W1[i*HD + j], acc);
    const float cur = __fadd_rn(acc, b1[j]);

    // mem1 recurrence -> 15-bit spike mask (exact op order)
    unsigned mask = 0u;
    float m1 = 0.0f;
    #pragma unroll
    for (int t = 0; t < NSNN; t++) {
        float sp1old = (__fsub_rn(m1, 1.0f) > 0.0f) ? 1.0f : 0.0f;
        m1 = __fsub_rn(__fadd_rn(__fmul_rn(0.9f, m1), cur), sp1old);
        if (__fsub_rn(m1, 1.0f) > 0.0f) mask |= (1u << t);
    }
    s_mask[j] = mask;
}

__device__ __attribute__((noinline)) void phase_w2(
    int j, int r, const float* __restrict__ W2, const float* __restrict__ b2)
{
    float* R = rowbase(r);
    unsigned* s_mask = (unsigned*)(R + OFF_MASK);
    float* s_mem2 = R + OFF_MEM2;

    // cache this row's 128 masks in 2 VGPRs/lane (lane = j & 63; both waves
    // of the pair hold identical copies)
    const int lane = j & 63;
    unsigned mlo = s_mask[lane];
    unsigned mhi = s_mask[64 + lane];

    // cur2[t] = spk[t] @ W2, one k-ascending pass, all 15 t at once.
    // fmaf(sv in {0,1}, w, acc) with sv=0 is an exact identity (acc stays
    // +0 under skips), so each cur2[t] equals the reference's sequential
    // chain bit-for-bit. Load AFTER the skip branch: skipped-k loads were
    // pure waste (~45% of W2 traffic).
    float cur2[NSNN];
    #pragma unroll
    for (int t = 0; t < NSNN; t++) cur2[t] = 0.0f;

    const float* W2j = W2 + j;
    #pragma unroll 1
    for (int k = 0; k < 64; k++) {
        unsigned m = (unsigned)__builtin_amdgcn_readlane((int)mlo, k);
        if (m == 0u) continue;           // wave-uniform scalar branch
        float w = W2j[(size_t)k * HD];
        #pragma unroll
        for (int t = 0; t < NSNN; t++) {
            float sv = __uint_as_float(((m >> t) & 1u) * 0x3f800000u);
            cur2[t] = fmaf(sv, w, cur2[t]);
        }
    }
    #pragma unroll 1
    for (int k = 0; k < 64; k++) {
        unsigned m = (unsigned)__builtin_amdgcn_readlane((int)mhi, k);
        if (m == 0u) continue;
        float w = W2j[(size_t)(64 + k) * HD];
        #pragma unroll
        for (int t = 0; t < NSNN; t++) {
            float sv = __uint_as_float(((m >> t) & 1u) * 0x3f800000u);
            cur2[t] = fmaf(sv, w, cur2[t]);
        }
    }

    // mem2 recurrence (exact op order)
    const float b2j = b2[j];
    float m2 = 0.0f;
    #pragma unroll
    for (int t = 0; t < NSNN; t++) {
        float c2 = __fadd_rn(cur2[t], b2j);
        float sp2old = (__fsub_rn(m2, 1.0f) > 0.0f) ? 1.0f : 0.0f;
        m2 = __fsub_rn(__fadd_rn(__fmul_rn(0.9f, m2), c2), sp2old);
    }
    s_mem2[j] = m2;
}

__device__ __attribute__((noinline)) void phase_decode(
    int j, int r, int cb, int h,
    const float* __restrict__ Wdec, const float* __restrict__ bdec,
    const float* __restrict__ Wunc, const float* __restrict__ bunc,
    const float* __restrict__ noise)
{
    float* R = rowbase(r);
    float* s_mem2  = R + OFF_MEM2;
    float* s_mu    = R + OFF_MU;
    float* s_state = R + OFF_STATE;
    float* s_x     = R + OFF_X;

    // decode, wave-split: threads 0..63 mean, 64..127 unc
    {
        const float* W    = (j < SS) ? Wdec : Wunc;
        const float* bias = (j < SS) ? bdec : bunc;
        int o = j & (SS - 1);
        float c = 0.0f;
        for (int n = 0; n < HD; n++)
            c = fmaf(s_mem2[n], W[n*SS + o], c);
        s_mu[j] = __fadd_rn(c, bias[o]);
    }
    __syncthreads();

    // sample next state; feeds next world step (s_state) and reward (s_x)
    if (j < SS) {
        float mean = s_mu[j];
        float u    = s_mu[SS + j];
        float var  = softplus_np(u);
        float sv   = sqrtf(__fadd_rn(var, 1e-8f));
        float nz   = noise[((size_t)cb*HH + h)*SS + j];
        float ns   = __fadd_rn(mean, __fmul_rn(nz, sv));
        s_state[j] = ns;
        s_x[j]     = ns;
    }
}

__device__ __attribute__((noinline)) void phase_reward(
    int j, int r, int h,
    const float* __restrict__ Wr1, const float* __restrict__ br1,
    const float* __restrict__ Wr2, const float* __restrict__ br2)
{
    float* R = rowbase(r);
    float* s_x   = R + OFF_X;
    float* s_h   = R + OFF_H;
    float* s_h2a = R + OFF_H2A;          // [HH][RH]

    if (j < RH) {
        float a = 0.0f;
        for (int i = 0; i < SS + AA; i++)
            a = fmaf(s_x[i], Wr1[i*RH + j], a);
        s_h[j] = fmaxf(__fadd_rn(a, br1[j]), 0.0f);
    }
    __syncthreads();
    if (j < RH) {
        float g = 0.0f;
        for (int i = 0; i < RH; i++)
            g = fmaf(s_h[i], Wr2[i*RH + j], g);
        s_h2a[h*RH + j] = fmaxf(__fadd_rn(g, br2[j]), 0.0f);
    }
}

__device__ __attribute__((noinline)) void phase_fold(
    int j, int r, int cb,
    const float* __restrict__ Wr3, const float* __restrict__ br3,
    float* __restrict__ cum)
{
    float* R = rowbase(r);
    float* s_h2a = R + OFF_H2A;
    float* s_r   = R + OFF_R;

    // all 10 h-chains in parallel (each its own sequential-k chain)
    if (j < HH) {
        float rr = 0.0f;
        for (int k = 0; k < RH; k++)
            rr = fmaf(s_h2a[j*RH + k], Wr3[k], rr);
        s_r[j] = __fadd_rn(rr, br3[0]);
    }
    __syncthreads();
    if (j == 0) {
        float total = 0.0f;
        for (int h = 0; h < HH; h++)
            total = __fadd_rn(total, s_r[h]);   // sequential sum over h
        cum[cb] = total;
    }
}

// One block = RT(=2) rows, full 10-step rollout + reward fused. 256 threads:
// row = tid>>7 (its own wave-pair), j = tid&127. State stays in LDS across
// h (zero global states traffic); weights shared across the row-pair via L1.
__global__ __launch_bounds__(256) void rollout_kernel(
    const float* __restrict__ current_state,
    const float* __restrict__ actions,
    const float* __restrict__ noise,
    const float* __restrict__ Wse, const float* __restrict__ bse,
    const float* __restrict__ Wae, const float* __restrict__ bae,
    const float* __restrict__ W1,  const float* __restrict__ b1,
    const float* __restrict__ W2,  const float* __restrict__ b2,
    const float* __restrict__ Wdec, const float* __restrict__ bdec,
    const float* __restrict__ Wunc, const float* __restrict__ bunc,
    const float* __restrict__ Wr1, const float* __restrict__ br1,
    const float* __restrict__ Wr2, const float* __restrict__ br2,
    const float* __restrict__ Wr3, const float* __restrict__ br3,
    float* __restrict__ cum)                   // [CB]
{
    const int r  = threadIdx.x >> 7;
    const int j  = threadIdx.x & 127;
    const int cb = blockIdx.x * RT + r;

    float* R = rowbase(r);
    if (j < SS) R[OFF_STATE + j] = current_state[(size_t)(cb % BB)*SS + j];

    #pragma unroll 1
    for (int h = 0; h < HH; h++) {
        __syncthreads();                 // s_state ready / prev readers done
        phase_encode(j, r, cb, h, Wse, bse, Wae, bae, actions);
        __syncthreads();
        phase_curmask(j, r, W1, b1);
        __syncthreads();
        phase_w2(j, r, W2, b2);
        __syncthreads();
        phase_decode(j, r, cb, h, Wdec, bdec, Wunc, bunc, noise);
        __syncthreads();
        phase_reward(j, r, h, Wr1, br1, Wr2, br2);
    }
    __syncthreads();
    phase_fold(j, r, cb, Wr3, br3, cum);
}

// One block per batch element b: f32 argmax over C (strict > = first max),
// gather best action. (Bit-exact, unchanged.)
__global__ __launch_bounds__(64) void select_kernel(
    const float* __restrict__ cum,      // [CB], cb = c*B + b
    const float* __restrict__ actions,  // [C,B,H,A]
    float* __restrict__ out)            // [B*H*A] actions then [B] values
{
    const int b = blockIdx.x;
    const int j = threadIdx.x;
    __shared__ int s_c;

    if (j == 0) {
        float best = cum[b];            // c = 0
        int bc = 0;
        for (int c = 1; c < CC; c++) {
            float v = cum[(size_t)c*BB + b];
            if (v > best) { best = v; bc = c; }
        }
        s_c = bc;
        out[(size_t)BB*HH*AA + b] = best;
    }
    __syncthreads();
    const int bc = s_c;
    const float* src = actions + ((size_t)bc*BB + b)*HH*AA;
    for (int i = j; i < HH*AA; i += 64) out[(size_t)b*HH*AA + i] = src[i];
}

extern "C" void kernel_launch(void* const* d_in, const int* in_sizes, int n_in,
                              void* d_out, int out_size, void* d_ws, size_t ws_size,
                              hipStream_t stream)
{
    const float* current_state = (const float*)d_in[0];
    const float* actions = (const float*)d_in[1];
    const float* noise   = (const float*)d_in[2];
    const float* Wse = (const float*)d_in[3];
    const float* bse = (const float*)d_in[4];
    const float* Wae = (const float*)d_in[5];
    const float* bae = (const float*)d_in[6];
    const float* W1  = (const float*)d_in[7];
    const float* b1  = (const float*)d_in[8];
    const float* W2  = (const float*)d_in[9];
    const float* b2  = (const float*)d_in[10];
    const float* Wdec = (const float*)d_in[11];
    const float* bdec = (const float*)d_in[12];
    const float* Wunc = (const float*)d_in[13];
    const float* bunc = (const float*)d_in[14];
    const float* Wr1 = (const float*)d_in[15];
    const float* br1 = (const float*)d_in[16];
    const float* Wr2 = (const float*)d_in[17];
    const float* br2 = (const float*)d_in[18];
    const float* Wr3 = (const float*)d_in[19];
    const float* br3 = (const float*)d_in[20];

    float* cum = (float*)d_ws;                          // 5120 f32

    const size_t smem_bytes = (size_t)RT * ROW_F * sizeof(float);  // ~12 KB
    rollout_kernel<<<CBR/RT, RT*HD, smem_bytes, stream>>>(
        current_state, actions, noise,
        Wse, bse, Wae, bae, W1, b1, W2, b2, Wdec, bdec, Wunc, bunc,
        Wr1, br1, Wr2, br2, Wr3, br3, cum);
    select_kernel<<<BB, 64, 0, stream>>>(cum, actions, (float*)d_out);
}

// Round 12
// 823.432 us; speedup vs baseline: 1.2269x; 1.2269x over previous
//
#include <hip/hip_runtime.h>
#include <math.h>

#define CC 20
#define BB 256
#define HH 10
#define SS 64
#define AA 16
#define HD 128
#define RH 64
#define CBR (CC*BB)      // 5120 rows
#define NSNN 15
#define RT 4             // rows per block, ONE WAVE per row

// Replicate npy_logaddexpf(u, 0.f): float32 chain, expf/log1pf at
// correctly-rounded level via f64 internals. (Verified bit-exact rounds 4-11.)
__device__ __forceinline__ float softplus_np(float u) {
    if (u > 0.0f) {
        float ef = (float)exp((double)(-u));
        float l1 = (float)log1p((double)ef);
        return __fadd_rn(u, l1);
    } else if (u < 0.0f) {
        float ef = (float)exp((double)u);
        return (float)log1p((double)ef);
    } else {
        return 0.69314718055994530942f;
    }
}

// One block = RT(=4) rows, ONE horizon step h, one 64-lane WAVE per row.
// Lane owns hidden units j=lane and j=lane+64 (2-way ILP in every chain).
// ZERO __syncthreads: all LDS producer->consumer pairs are intra-wave,
// ordered by lgkmcnt automatically; each row's LDS region is touched only
// by its own wave. Spike masks stay in registers (lane k holds units k and
// 64+k -> readlane serves the whole row).
//
// Reward for step h fused in (s_x on hand); cum accumulated across the 10
// dispatches in ascending-h order — identical __fadd_rn sequence to the
// reference, so still bit-exact.
//
// All dots are single sequential-k fmaf chains; elementwise ops separately
// rounded (__f*_rn) — bit-exact vs np-f32 (verified rounds 4-11). W2 k-loops
// pinned rolled (#pragma unroll 1) to block the round-5/7 VGPR blowup;
// t-loops fully unrolled so cur2[] stays in registers.
__global__ __launch_bounds__(256) void world_kernel(
    int h,
    const float* __restrict__ current_state,   // [B,S]
    const float* __restrict__ actions,         // [C,B,H,A]
    const float* __restrict__ noise,           // [C,B,H,S]
    const float* __restrict__ Wse, const float* __restrict__ bse,
    const float* __restrict__ Wae, const float* __restrict__ bae,
    const float* __restrict__ W1,  const float* __restrict__ b1,
    const float* __restrict__ W2,  const float* __restrict__ b2,
    const float* __restrict__ Wdec, const float* __restrict__ bdec,
    const float* __restrict__ Wunc, const float* __restrict__ bunc,
    const float* __restrict__ Wr1, const float* __restrict__ br1,
    const float* __restrict__ Wr2, const float* __restrict__ br2,
    const float* __restrict__ Wr3, const float* __restrict__ br3,
    float* __restrict__ states,                // [H, CB, S]
    float* __restrict__ cum)                   // [CB]
{
    const int r    = threadIdx.x >> 6;         // row (wave) within block
    const int lane = threadIdx.x & 63;
    const int cb   = blockIdx.x * RT + r;

    __shared__ float s_state[RT][SS];
    __shared__ float s_sae[RT][2*HD];
    __shared__ float s_mem2[RT][HD];
    __shared__ float s_x[RT][SS + AA];
    __shared__ float s_h[RT][RH];
    __shared__ float s_h2[RT][RH];

    s_state[r][lane] = (h == 0) ? current_state[(size_t)(cb % BB)*SS + lane]
                                : states[((size_t)(h-1)*CBR + cb)*SS + lane];
    // intra-wave LDS dep: hardware lgkmcnt orders write->read, no barrier

    // ---- se = relu(state @ Wse + bse): two sequential-k chains (units
    // lane, lane+64), interleaved for ILP — each chain's op order unchanged
    float a0 = 0.0f, a1 = 0.0f;
    for (int i = 0; i < SS; i++) {
        float st = s_state[r][i];                    // broadcast read
        a0 = fmaf(st, Wse[i*HD + lane],      a0);
        a1 = fmaf(st, Wse[i*HD + 64 + lane], a1);
    }
    float se0 = fmaxf(__fadd_rn(a0, bse[lane]),      0.0f);
    float se1 = fmaxf(__fadd_rn(a1, bse[64 + lane]), 0.0f);

    // ---- ae = relu(act @ Wae + bae)
    const float* act = actions + ((size_t)cb*HH + h)*AA;
    float e0 = 0.0f, e1 = 0.0f;
    for (int i = 0; i < AA; i++) {
        float av = act[i];
        e0 = fmaf(av, Wae[i*HD + lane],      e0);
        e1 = fmaf(av, Wae[i*HD + 64 + lane], e1);
    }
    float ae0 = fmaxf(__fadd_rn(e0, bae[lane]),      0.0f);
    float ae1 = fmaxf(__fadd_rn(e1, bae[64 + lane]), 0.0f);

    s_sae[r][lane]            = se0;
    s_sae[r][64 + lane]       = se1;
    s_sae[r][HD + lane]       = ae0;
    s_sae[r][HD + 64 + lane]  = ae1;

    // ---- cur = concat(se, ae) @ W1 + b1: two 256-chains, interleaved
    float c0 = 0.0f, c1 = 0.0f;
    for (int i = 0; i < 2*HD; i++) {
        float v = s_sae[r][i];                       // broadcast read
        c0 = fmaf(v, W1[i*HD + lane],      c0);
        c1 = fmaf(v, W1[i*HD + 64 + lane], c1);
    }
    const float cur0 = __fadd_rn(c0, b1[lane]);
    const float cur1 = __fadd_rn(c1, b1[64 + lane]);

    // ---- mem1 recurrence -> 15-bit spike masks, both units (exact order)
    unsigned mask0 = 0u, mask1 = 0u;
    {
        float m1a = 0.0f, m1b = 0.0f;
        #pragma unroll
        for (int t = 0; t < NSNN; t++) {
            float spa = (__fsub_rn(m1a, 1.0f) > 0.0f) ? 1.0f : 0.0f;
            m1a = __fsub_rn(__fadd_rn(__fmul_rn(0.9f, m1a), cur0), spa);
            if (__fsub_rn(m1a, 1.0f) > 0.0f) mask0 |= (1u << t);
            float spb = (__fsub_rn(m1b, 1.0f) > 0.0f) ? 1.0f : 0.0f;
            m1b = __fsub_rn(__fadd_rn(__fmul_rn(0.9f, m1b), cur1), spb);
            if (__fsub_rn(m1b, 1.0f) > 0.0f) mask1 |= (1u << t);
        }
    }
    // lane k's mask0/mask1 ARE units k / 64+k — readlane, no LDS round-trip.

    // ---- cur2[t] = spk[t] @ W2 for both units, one k-ascending pass.
    // fmaf(sv in {0,1}, w, acc) with sv=0 is an exact identity, so each
    // chain equals the reference's sequential chain bit-for-bit; m==0 units
    // skipped by wave-uniform scalar branch (their terms are exact zeros).
    float c2a[NSNN], c2b[NSNN];
    #pragma unroll
    for (int t = 0; t < NSNN; t++) { c2a[t] = 0.0f; c2b[t] = 0.0f; }

    const float* W2a = W2 + lane;
    const float* W2b = W2 + 64 + lane;
    #pragma unroll 1
    for (int k = 0; k < 64; k++) {
        unsigned m = (unsigned)__builtin_amdgcn_readlane((int)mask0, k);
        if (m == 0u) continue;
        float wa = W2a[(size_t)k * HD];
        float wb = W2b[(size_t)k * HD];
        #pragma unroll
        for (int t = 0; t < NSNN; t++) {
            float sv = __uint_as_float(((m >> t) & 1u) * 0x3f800000u);
            c2a[t] = fmaf(sv, wa, c2a[t]);
            c2b[t] = fmaf(sv, wb, c2b[t]);
        }
    }
    #pragma unroll 1
    for (int k = 0; k < 64; k++) {
        unsigned m = (unsigned)__builtin_amdgcn_readlane((int)mask1, k);
        if (m == 0u) continue;
        float wa = W2a[(size_t)(64 + k) * HD];
        float wb = W2b[(size_t)(64 + k) * HD];
        #pragma unroll
        for (int t = 0; t < NSNN; t++) {
            float sv = __uint_as_float(((m >> t) & 1u) * 0x3f800000u);
            c2a[t] = fmaf(sv, wa, c2a[t]);
            c2b[t] = fmaf(sv, wb, c2b[t]);
        }
    }

    // ---- mem2 recurrence, both units (exact op order)
    {
        const float b2a = b2[lane], b2b = b2[64 + lane];
        float m2a = 0.0f, m2b = 0.0f;
        #pragma unroll
        for (int t = 0; t < NSNN; t++) {
            float ca = __fadd_rn(c2a[t], b2a);
            float spa = (__fsub_rn(m2a, 1.0f) > 0.0f) ? 1.0f : 0.0f;
            m2a = __fsub_rn(__fadd_rn(__fmul_rn(0.9f, m2a), ca), spa);
            float cbv = __fadd_rn(c2b[t], b2b);
            float spb = (__fsub_rn(m2b, 1.0f) > 0.0f) ? 1.0f : 0.0f;
            m2b = __fsub_rn(__fadd_rn(__fmul_rn(0.9f, m2b), cbv), spb);
        }
        s_mem2[r][lane]      = m2a;
        s_mem2[r][64 + lane] = m2b;
    }

    // ---- decode: lane computes mean[lane] AND u[lane] (two chains, ILP)
    float dm = 0.0f, du = 0.0f;
    for (int n = 0; n < HD; n++) {
        float mv = s_mem2[r][n];                     // broadcast read
        dm = fmaf(mv, Wdec[n*SS + lane], dm);
        du = fmaf(mv, Wunc[n*SS + lane], du);
    }
    float mean = __fadd_rn(dm, bdec[lane]);
    float u    = __fadd_rn(du, bunc[lane]);

    // ---- sample next state
    float var = softplus_np(u);
    float sv  = sqrtf(__fadd_rn(var, 1e-8f));
    float nz  = noise[((size_t)cb*HH + h)*SS + lane];
    float ns  = __fadd_rn(mean, __fmul_rn(nz, sv));
    states[((size_t)h*CBR + cb)*SS + lane] = ns;

    // ---- reward for step h (fused): x = [ns, act]
    s_x[r][lane] = ns;
    if (lane < AA) s_x[r][SS + lane] = act[lane];

    float ra = 0.0f;
    for (int i = 0; i < SS + AA; i++)
        ra = fmaf(s_x[r][i], Wr1[i*RH + lane], ra);
    s_h[r][lane] = fmaxf(__fadd_rn(ra, br1[lane]), 0.0f);

    float rg = 0.0f;
    for (int i = 0; i < RH; i++)
        rg = fmaf(s_h[r][i], Wr2[i*RH + lane], rg);
    s_h2[r][lane] = fmaxf(__fadd_rn(rg, br2[lane]), 0.0f);

    // fold r_h (redundant across lanes via broadcast reads; lane 0 commits).
    // cum accumulates across the 10 dispatches in ascending-h order — the
    // same sequential __fadd_rn chain as the reference.
    float rr = 0.0f;
    for (int k = 0; k < RH; k++)
        rr = fmaf(s_h2[r][k], Wr3[k], rr);
    rr = __fadd_rn(rr, br3[0]);
    if (lane == 0)
        cum[cb] = (h == 0) ? rr : __fadd_rn(cum[cb], rr);
}

// One block per batch element b: f32 argmax over C (strict > = first max),
// gather best action. (Bit-exact, unchanged.)
__global__ __launch_bounds__(64) void select_kernel(
    const float* __restrict__ cum,      // [CB], cb = c*B + b
    const float* __restrict__ actions,  // [C,B,H,A]
    float* __restrict__ out)            // [B*H*A] actions then [B] values
{
    const int b = blockIdx.x;
    const int j = threadIdx.x;
    __shared__ int s_c;

    if (j == 0) {
        float best = cum[b];            // c = 0
        int bc = 0;
        for (int c = 1; c < CC; c++) {
            float v = cum[(size_t)c*BB + b];
            if (v > best) { best = v; bc = c; }
        }
        s_c = bc;
        out[(size_t)BB*HH*AA + b] = best;
    }
    __syncthreads();
    const int bc = s_c;
    const float* src = actions + ((size_t)bc*BB + b)*HH*AA;
    for (int i = j; i < HH*AA; i += 64) out[(size_t)b*HH*AA + i] = src[i];
}

extern "C" void kernel_launch(void* const* d_in, const int* in_sizes, int n_in,
                              void* d_out, int out_size, void* d_ws, size_t ws_size,
                              hipStream_t stream)
{
    const float* current_state = (const float*)d_in[0];
    const float* actions = (const float*)d_in[1];
    const float* noise   = (const float*)d_in[2];
    const float* Wse = (const float*)d_in[3];
    const float* bse = (const float*)d_in[4];
    const float* Wae = (const float*)d_in[5];
    const float* bae = (const float*)d_in[6];
    const float* W1  = (const float*)d_in[7];
    const float* b1  = (const float*)d_in[8];
    const float* W2  = (const float*)d_in[9];
    const float* b2  = (const float*)d_in[10];
    const float* Wdec = (const float*)d_in[11];
    const float* bdec = (const float*)d_in[12];
    const float* Wunc = (const float*)d_in[13];
    const float* bunc = (const float*)d_in[14];
    const float* Wr1 = (const float*)d_in[15];
    const float* br1 = (const float*)d_in[16];
    const float* Wr2 = (const float*)d_in[17];
    const float* br2 = (const float*)d_in[18];
    const float* Wr3 = (const float*)d_in[19];
    const float* br3 = (const float*)d_in[20];

    float* states = (float*)d_ws;                       // 10*5120*64 f32 = 13.1 MB
    float* cum    = states + (size_t)HH*CBR*SS;         // 5120 f32

    for (int h = 0; h < HH; h++) {
        world_kernel<<<CBR/RT, RT*64, 0, stream>>>(h, current_state, actions, noise,
            Wse, bse, Wae, bae, W1, b1, W2, b2, Wdec, bdec, Wunc, bunc,
            Wr1, br1, Wr2, br2, Wr3, br3, states, cum);
    }
    select_kernel<<<BB, 64, 0, stream>>>(cum, actions, (float*)d_out);
}